// Round 8
// baseline (443.764 us; speedup 1.0000x reference)
//
#include <hip/hip_runtime.h>
#include <stdint.h>
#include <stddef.h>

// ---------------- types / helpers ----------------
typedef __attribute__((ext_vector_type(8))) short bf16x8;
typedef __attribute__((ext_vector_type(4))) float f32x4;

#define B_ 2
#define S_ 2048
#define HID_ 2048
#define NH_ 16
#define NKV_ 8
#define HD_ 128
#define SCALE_ 0.08838834764831843f

__device__ __forceinline__ unsigned short f2bf(float f) {
  union { float f; unsigned int u; } v; v.f = f;
  unsigned int r = v.u + 0x7fffu + ((v.u >> 16) & 1u);  // RNE
  return (unsigned short)(r >> 16);
}

// async global->LDS, 16B per lane. Dest must be wave-uniform base (HW adds lane*16).
__device__ __forceinline__ void gload16(const void* g, void* l) {
  __builtin_amdgcn_global_load_lds(
      (const __attribute__((address_space(1))) unsigned int*)g,
      (__attribute__((address_space(3))) unsigned int*)l, 16, 0, 0);
}

// ---------------- fp32 -> bf16 convert ----------------
__global__ __launch_bounds__(256) void cvt_bf16(const float* __restrict__ src,
                                                unsigned short* __restrict__ dst,
                                                int n4) {
  int i = blockIdx.x * 256 + threadIdx.x;
  if (i < n4) {
    float4 v = ((const float4*)src)[i];
    ushort4 o;
    o.x = f2bf(v.x); o.y = f2bf(v.y); o.z = f2bf(v.z); o.w = f2bf(v.w);
    ((ushort4*)dst)[i] = o;
  }
}

// ---------------- bf16 GEMM, C = A(MxK) * Bw(NxK)^T, fp32 out ----------------
// 128x128 tile, BK=64, 4 waves (2x2), 16x16x32 MFMA.
// LDS tiles [128][64] bf16 (128B rows), XOR-swizzle byte^=((row&7)<<4) via
// pre-swizzled global source (LDS dest stays linear for global_load_lds).
__global__ __launch_bounds__(256) void gemm_bt(const unsigned short* __restrict__ A,
                                               const unsigned short* __restrict__ Bw,
                                               float* __restrict__ C,
                                               int M, int N, int K) {
  __shared__ __align__(16) char lds[32768];  // A:0..16383, B:16384..32767
  const int t = threadIdx.x, w = t >> 6, lane = t & 63;
  const int m0 = blockIdx.y * 128, n0 = blockIdx.x * 128;
  const int wr = w >> 1, wc = w & 1;
  const int l15 = lane & 15, l4 = lane >> 4;

  f32x4 acc[4][4];
#pragma unroll
  for (int i = 0; i < 4; ++i)
#pragma unroll
    for (int j = 0; j < 4; ++j) acc[i][j] = (f32x4){0.f, 0.f, 0.f, 0.f};

  const int nk = K >> 6;
  for (int kt = 0; kt < nk; ++kt) {
    // stage A tile (16KB) : 4 instr/wave, 8 rows per instr
#pragma unroll
    for (int j = 0; j < 4; ++j) {
      int ob = ((w * 4 + j) << 10) + (lane << 4);
      int row = ob >> 7, inrow = ob & 127;
      int src = inrow ^ ((row & 7) << 4);
      gload16((const char*)A + ((size_t)(m0 + row) * K + kt * 64) * 2 + src,
              lds + ((w * 4 + j) << 10));
    }
    // stage B tile
#pragma unroll
    for (int j = 0; j < 4; ++j) {
      int ob = ((w * 4 + j) << 10) + (lane << 4);
      int row = ob >> 7, inrow = ob & 127;
      int src = inrow ^ ((row & 7) << 4);
      gload16((const char*)Bw + ((size_t)(n0 + row) * K + kt * 64) * 2 + src,
              lds + 16384 + ((w * 4 + j) << 10));
    }
    __syncthreads();
#pragma unroll
    for (int c = 0; c < 2; ++c) {
      bf16x8 af[4], bfr[4];
#pragma unroll
      for (int i = 0; i < 4; ++i) {
        int rowl = wr * 64 + i * 16 + l15;
        int inr = c * 64 + l4 * 16;
        af[i] = *(const bf16x8*)(lds + rowl * 128 + (inr ^ ((rowl & 7) << 4)));
      }
#pragma unroll
      for (int j = 0; j < 4; ++j) {
        int rowl = wc * 64 + j * 16 + l15;
        int inr = c * 64 + l4 * 16;
        bfr[j] = *(const bf16x8*)(lds + 16384 + rowl * 128 + (inr ^ ((rowl & 7) << 4)));
      }
#pragma unroll
      for (int i = 0; i < 4; ++i)
#pragma unroll
        for (int j = 0; j < 4; ++j)
          acc[i][j] = __builtin_amdgcn_mfma_f32_16x16x32_bf16(af[i], bfr[j], acc[i][j], 0, 0, 0);
    }
    __syncthreads();
  }
  // epilogue: C/D layout col=lane&15, row=(lane>>4)*4+reg
#pragma unroll
  for (int i = 0; i < 4; ++i)
#pragma unroll
    for (int j = 0; j < 4; ++j)
#pragma unroll
      for (int r = 0; r < 4; ++r) {
        int m = m0 + wr * 64 + i * 16 + l4 * 4 + r;
        int n = n0 + wc * 64 + j * 16 + l15;
        C[(size_t)m * N + n] = acc[i][j][r];
      }
}

// ---------------- fused RMSNorm + RoPE ----------------
// one block per (b,s); 8 lanes per head; q heads 0-15, k heads 16-23.
__global__ __launch_bounds__(256) void norm_rope(const float* __restrict__ QKV,
                                                 const float* __restrict__ cosT,
                                                 const float* __restrict__ sinT,
                                                 const float* __restrict__ qw,
                                                 const float* __restrict__ kw,
                                                 unsigned short* __restrict__ qo,
                                                 unsigned short* __restrict__ ko) {
  int bs = blockIdx.x;
  int b = bs >> 11, s = bs & 2047;
  int t = threadIdx.x, hu = t >> 3, l8 = t & 7;
  if (hu >= 24) return;
  bool isq = hu < 16;
  int h = isq ? hu : hu - 16;
  const float* x = QKV + (size_t)bs * 4096 + (isq ? h * 128 : 2048 + h * 128);
  int d0 = l8 * 8;
  float x1[8] __attribute__((aligned(16)));
  float x2[8] __attribute__((aligned(16)));
  *(float4*)(x1) = *(const float4*)(x + d0);
  *(float4*)(x1 + 4) = *(const float4*)(x + d0 + 4);
  *(float4*)(x2) = *(const float4*)(x + d0 + 64);
  *(float4*)(x2 + 4) = *(const float4*)(x + d0 + 68);
  float ss = 0.f;
#pragma unroll
  for (int j = 0; j < 8; ++j) ss += x1[j] * x1[j] + x2[j] * x2[j];
  ss += __shfl_xor(ss, 1);
  ss += __shfl_xor(ss, 2);
  ss += __shfl_xor(ss, 4);
  float rstd = rsqrtf(ss * 0.0078125f + 1e-6f);
  const float* wn = isq ? qw : kw;
  float c[8] __attribute__((aligned(16)));
  float sn[8] __attribute__((aligned(16)));
  *(float4*)(c) = *(const float4*)(cosT + s * 64 + d0);
  *(float4*)(c + 4) = *(const float4*)(cosT + s * 64 + d0 + 4);
  *(float4*)(sn) = *(const float4*)(sinT + s * 64 + d0);
  *(float4*)(sn + 4) = *(const float4*)(sinT + s * 64 + d0 + 4);
  bf16x8 o1, o2;
#pragma unroll
  for (int j = 0; j < 8; ++j) {
    float a = x1[j] * rstd * wn[d0 + j];
    float bb = x2[j] * rstd * wn[d0 + 64 + j];
    o1[j] = (short)f2bf(a * c[j] - bb * sn[j]);
    o2[j] = (short)f2bf(bb * c[j] + a * sn[j]);
  }
  unsigned short* dst = isq ? qo + ((size_t)(b * 16 + h) * 2048 + s) * 128
                            : ko + ((size_t)(b * 8 + h) * 2048 + s) * 128;
  *(bf16x8*)(dst + d0) = o1;
  *(bf16x8*)(dst + d0 + 64) = o2;
}

// ---------------- V transpose: qkv f32 [.,s,3072+hkv*128+d] -> vT bf16 [b,hkv,d,s]
__global__ __launch_bounds__(256) void transpose_v(const float* __restrict__ QKV,
                                                   unsigned short* __restrict__ vT) {
  __shared__ unsigned short tile[64][68];
  int bid = blockIdx.x;  // 1024 = 16 heads * 32 s-tiles * 2 d-tiles
  int hid = bid >> 6;
  int st = (bid >> 1) & 31, dt = bid & 1;
  int b = hid >> 3, hkv = hid & 7;
  int t = threadIdx.x;
#pragma unroll
  for (int i = 0; i < 16; ++i) {
    int idx = t + i * 256;
    int sl = idx >> 6, dl = idx & 63;
    float v = QKV[(size_t)(b * 2048 + st * 64 + sl) * 4096 + 3072 + hkv * 128 + dt * 64 + dl];
    tile[sl][dl] = f2bf(v);
  }
  __syncthreads();
#pragma unroll
  for (int i = 0; i < 16; ++i) {
    int idx = t + i * 256;
    int dl = idx >> 6, sl = idx & 63;
    vT[((size_t)(b * 8 + hkv) * 128 + dt * 64 + dl) * 2048 + st * 64 + sl] = tile[sl][dl];
  }
}

// ---------------- causal GQA flash attention ----------------
// grid (qtile=32, h=16, b=2), 256 thr = 4 waves, wave w owns q rows qt*64+w*16..+15
__global__ __launch_bounds__(256) void attn_fwd(const unsigned short* __restrict__ Q,
                                                const unsigned short* __restrict__ Kb,
                                                const unsigned short* __restrict__ Vt,
                                                unsigned short* __restrict__ Ao) {
  __shared__ __align__(16) char lds[41984];  // K:16KB, VT:16KB, P: 4x2304B
  const int qt = blockIdx.x, h = blockIdx.y, b = blockIdx.z;
  const int hkv = h >> 1;
  const int t = threadIdx.x, w = t >> 6, lane = t & 63;
  const int l15 = lane & 15, l4 = lane >> 4;
  const int qrow0 = qt * 64;

  // Q fragments in regs: row = w*16 + (lane&15), k-chunks of 32
  bf16x8 qf[4];
  const unsigned short* qp = Q + ((size_t)(b * 16 + h) * 2048 + qrow0 + w * 16 + l15) * 128;
#pragma unroll
  for (int c = 0; c < 4; ++c) qf[c] = *(const bf16x8*)(qp + c * 32 + l4 * 8);

  float mrow[4], lrow[4];
  f32x4 o[8];
#pragma unroll
  for (int r = 0; r < 4; ++r) { mrow[r] = -1e30f; lrow[r] = 0.f; }
#pragma unroll
  for (int dn = 0; dn < 8; ++dn) o[dn] = (f32x4){0.f, 0.f, 0.f, 0.f};

  const unsigned short* Kg = Kb + ((size_t)(b * 8 + hkv) * 2048) * 128;
  const unsigned short* Vg = Vt + ((size_t)(b * 8 + hkv) * 128) * 2048;
  char* Pb = lds + 32768 + w * 2304;

  for (int tt = 0; tt <= qt; ++tt) {
    __syncthreads();  // prev iter's PV reads done before restage
    // stage K tile [64][256B rows], swizzled source
#pragma unroll
    for (int j = 0; j < 4; ++j) {
      int ob = ((w * 4 + j) << 10) + (lane << 4);
      int row = ob >> 8, inrow = ob & 255;
      int src = inrow ^ ((row & 7) << 4);
      gload16((const char*)(Kg + (size_t)tt * 64 * 128) + row * 256 + src,
              lds + ((w * 4 + j) << 10));
    }
    // stage VT tile [128][128B rows], swizzled source
#pragma unroll
    for (int j = 0; j < 4; ++j) {
      int ob = ((w * 4 + j) << 10) + (lane << 4);
      int row = ob >> 7, inrow = ob & 127;
      int src = inrow ^ ((row & 7) << 4);
      gload16((const char*)Vg + (size_t)row * 4096 + tt * 128 + src,
              lds + 16384 + ((w * 4 + j) << 10));
    }
    __syncthreads();

    // QK^T: scores [16 q][64 kv] per wave
    f32x4 sacc[4];
#pragma unroll
    for (int n = 0; n < 4; ++n) sacc[n] = (f32x4){0.f, 0.f, 0.f, 0.f};
#pragma unroll
    for (int c = 0; c < 4; ++c) {
#pragma unroll
      for (int n = 0; n < 4; ++n) {
        int rowl = n * 16 + l15;
        int inr = c * 64 + l4 * 16;
        bf16x8 kf = *(const bf16x8*)(lds + rowl * 256 + (inr ^ ((rowl & 7) << 4)));
        sacc[n] = __builtin_amdgcn_mfma_f32_16x16x32_bf16(qf[c], kf, sacc[n], 0, 0, 0);
      }
    }

    // online softmax (lane holds rows l4*4+r, cols n*16+l15)
    float sc[4][4];
    bool diag = (tt == qt);
#pragma unroll
    for (int n = 0; n < 4; ++n)
#pragma unroll
      for (int r = 0; r < 4; ++r) {
        float v = sacc[n][r] * SCALE_;
        if (diag && (tt * 64 + n * 16 + l15 > qrow0 + w * 16 + l4 * 4 + r)) v = -1e30f;
        sc[n][r] = v;
      }
    float al[4];
#pragma unroll
    for (int r = 0; r < 4; ++r) {
      float tm = fmaxf(fmaxf(sc[0][r], sc[1][r]), fmaxf(sc[2][r], sc[3][r]));
      tm = fmaxf(tm, __shfl_xor(tm, 1));
      tm = fmaxf(tm, __shfl_xor(tm, 2));
      tm = fmaxf(tm, __shfl_xor(tm, 4));
      tm = fmaxf(tm, __shfl_xor(tm, 8));
      float mn = fmaxf(mrow[r], tm);
      al[r] = __expf(mrow[r] - mn);
      mrow[r] = mn;
    }
    float rs[4] = {0.f, 0.f, 0.f, 0.f};
#pragma unroll
    for (int n = 0; n < 4; ++n)
#pragma unroll
      for (int r = 0; r < 4; ++r) {
        float p = __expf(sc[n][r] - mrow[r]);
        sc[n][r] = p;
        rs[r] += p;
      }
#pragma unroll
    for (int r = 0; r < 4; ++r) {
      rs[r] += __shfl_xor(rs[r], 1);
      rs[r] += __shfl_xor(rs[r], 2);
      rs[r] += __shfl_xor(rs[r], 4);
      rs[r] += __shfl_xor(rs[r], 8);
      lrow[r] = lrow[r] * al[r] + rs[r];
    }
#pragma unroll
    for (int dn = 0; dn < 8; ++dn)
#pragma unroll
      for (int r = 0; r < 4; ++r) o[dn][r] *= al[r];

    // P -> LDS (per-wave [16][72] padded bf16), then re-fragment as A-operand
    unsigned short* Pp = (unsigned short*)Pb;
#pragma unroll
    for (int n = 0; n < 4; ++n)
#pragma unroll
      for (int r = 0; r < 4; ++r)
        Pp[(l4 * 4 + r) * 72 + n * 16 + l15] = f2bf(sc[n][r]);
    __syncthreads();

    // PV: O += P[16][64] * V[64][128]
#pragma unroll
    for (int c2 = 0; c2 < 2; ++c2) {
      bf16x8 pf = *(const bf16x8*)(Pb + l15 * 144 + c2 * 64 + l4 * 16);
#pragma unroll
      for (int dn = 0; dn < 8; ++dn) {
        int rowv = dn * 16 + l15;
        int inr = c2 * 64 + l4 * 16;
        bf16x8 vf = *(const bf16x8*)(lds + 16384 + rowv * 128 + (inr ^ ((rowv & 7) << 4)));
        o[dn] = __builtin_amdgcn_mfma_f32_16x16x32_bf16(pf, vf, o[dn], 0, 0, 0);
      }
    }
  }

  // normalize + write bf16 attn out [B,S,NH*HD]
#pragma unroll
  for (int r = 0; r < 4; ++r) {
    float inv = 1.f / lrow[r];
#pragma unroll
    for (int dn = 0; dn < 8; ++dn) {
      Ao[(size_t)(b * 2048 + qrow0 + w * 16 + l4 * 4 + r) * 2048 + h * 128 + dn * 16 + l15] =
          f2bf(o[dn][r] * inv);
    }
  }
}

// ---------------- launch ----------------
extern "C" void kernel_launch(void* const* d_in, const int* in_sizes, int n_in,
                              void* d_out, int out_size, void* d_ws, size_t ws_size,
                              hipStream_t stream) {
  const float* hidden = (const float*)d_in[0];
  const float* cosT = (const float*)d_in[1];
  const float* sinT = (const float*)d_in[2];
  const float* wqkv = (const float*)d_in[3];
  const float* qw = (const float*)d_in[4];
  const float* kw = (const float*)d_in[5];
  const float* wo = (const float*)d_in[6];
  float* out = (float*)d_out;
  char* ws = (char*)d_ws;

  unsigned short* Xb = (unsigned short*)(ws);                    // 16 MB
  unsigned short* Wqkvb = (unsigned short*)(ws + 16777216);      // 16 MB
  unsigned short* Wob = (unsigned short*)(ws + 33554432);        // 8 MB
  float* QKV = (float*)(ws + 41943040);                          // 64 MB
  unsigned short* Qb = (unsigned short*)(ws + 109051904);        // 16 MB
  unsigned short* Kbuf = (unsigned short*)(ws + 125829120);      // 8 MB
  unsigned short* VT = (unsigned short*)(ws + 134217728);        // 8 MB
  unsigned short* An = (unsigned short*)(ws + 142606336);        // 16 MB

  cvt_bf16<<<8192, 256, 0, stream>>>(hidden, Xb, 2097152);
  cvt_bf16<<<8192, 256, 0, stream>>>(wqkv, Wqkvb, 2097152);
  cvt_bf16<<<4096, 256, 0, stream>>>(wo, Wob, 1048576);

  gemm_bt<<<dim3(32, 32), 256, 0, stream>>>(Xb, Wqkvb, QKV, 4096, 4096, 2048);

  norm_rope<<<4096, 256, 0, stream>>>(QKV, cosT, sinT, qw, kw, Qb, Kbuf);
  transpose_v<<<1024, 256, 0, stream>>>(QKV, VT);

  attn_fwd<<<dim3(32, 16, 2), 256, 0, stream>>>(Qb, Kbuf, VT, An);

  gemm_bt<<<dim3(16, 32), 256, 0, stream>>>(An, Wob, out, 4096, 2048, 2048);
}

// Round 10
// 373.941 us; speedup vs baseline: 1.1867x; 1.1867x over previous
//
#include <hip/hip_runtime.h>
#include <stdint.h>
#include <stddef.h>

// ---------------- types / helpers ----------------
typedef __attribute__((ext_vector_type(8))) short bf16x8;
typedef __attribute__((ext_vector_type(4))) float f32x4;

#define B_ 2
#define S_ 2048
#define HID_ 2048
#define NH_ 16
#define NKV_ 8
#define HD_ 128
#define SCALE_ 0.08838834764831843f

__device__ __forceinline__ unsigned short f2bf(float f) {
  union { float f; unsigned int u; } v; v.f = f;
  unsigned int r = v.u + 0x7fffu + ((v.u >> 16) & 1u);  // RNE
  return (unsigned short)(r >> 16);
}

// async global->LDS, 16B per lane. Dest must be wave-uniform base (HW adds lane*16).
__device__ __forceinline__ void gload16(const void* g, void* l) {
  __builtin_amdgcn_global_load_lds(
      (const __attribute__((address_space(1))) unsigned int*)g,
      (__attribute__((address_space(3))) unsigned int*)l, 16, 0, 0);
}

// ---------------- fp32 -> bf16 convert ----------------
__global__ __launch_bounds__(256) void cvt_bf16(const float* __restrict__ src,
                                                unsigned short* __restrict__ dst,
                                                int n4) {
  int i = blockIdx.x * 256 + threadIdx.x;
  if (i < n4) {
    float4 v = ((const float4*)src)[i];
    ushort4 o;
    o.x = f2bf(v.x); o.y = f2bf(v.y); o.z = f2bf(v.z); o.w = f2bf(v.w);
    ((ushort4*)dst)[i] = o;
  }
}

// ---------------- bf16 GEMM, C = A(MxK) * Bw(NxK)^T, fp32 out ----------------
// 128x128 tile, BK=64, 4 waves (2x2), 16x16x32 MFMA.  (m97-class structure)
__global__ __launch_bounds__(256) void gemm_bt(const unsigned short* __restrict__ A,
                                               const unsigned short* __restrict__ Bw,
                                               float* __restrict__ C,
                                               int M, int N, int K) {
  __shared__ __align__(16) char lds[32768];  // A:0..16383, B:16384..32767
  const int t = threadIdx.x, w = t >> 6, lane = t & 63;
  const int m0 = blockIdx.y * 128, n0 = blockIdx.x * 128;
  const int wr = w >> 1, wc = w & 1;
  const int l15 = lane & 15, l4 = lane >> 4;

  f32x4 acc[4][4];
#pragma unroll
  for (int i = 0; i < 4; ++i)
#pragma unroll
    for (int j = 0; j < 4; ++j) acc[i][j] = (f32x4){0.f, 0.f, 0.f, 0.f};

  const int nk = K >> 6;
  for (int kt = 0; kt < nk; ++kt) {
#pragma unroll
    for (int j = 0; j < 4; ++j) {
      int ob = ((w * 4 + j) << 10) + (lane << 4);
      int row = ob >> 7, inrow = ob & 127;
      int src = inrow ^ ((row & 7) << 4);
      gload16((const char*)A + ((size_t)(m0 + row) * K + kt * 64) * 2 + src,
              lds + ((w * 4 + j) << 10));
    }
#pragma unroll
    for (int j = 0; j < 4; ++j) {
      int ob = ((w * 4 + j) << 10) + (lane << 4);
      int row = ob >> 7, inrow = ob & 127;
      int src = inrow ^ ((row & 7) << 4);
      gload16((const char*)Bw + ((size_t)(n0 + row) * K + kt * 64) * 2 + src,
              lds + 16384 + ((w * 4 + j) << 10));
    }
    __syncthreads();
#pragma unroll
    for (int c = 0; c < 2; ++c) {
      bf16x8 af[4], bfr[4];
#pragma unroll
      for (int i = 0; i < 4; ++i) {
        int rowl = wr * 64 + i * 16 + l15;
        int inr = c * 64 + l4 * 16;
        af[i] = *(const bf16x8*)(lds + rowl * 128 + (inr ^ ((rowl & 7) << 4)));
      }
#pragma unroll
      for (int j = 0; j < 4; ++j) {
        int rowl = wc * 64 + j * 16 + l15;
        int inr = c * 64 + l4 * 16;
        bfr[j] = *(const bf16x8*)(lds + 16384 + rowl * 128 + (inr ^ ((rowl & 7) << 4)));
      }
#pragma unroll
      for (int i = 0; i < 4; ++i)
#pragma unroll
        for (int j = 0; j < 4; ++j)
          acc[i][j] = __builtin_amdgcn_mfma_f32_16x16x32_bf16(af[i], bfr[j], acc[i][j], 0, 0, 0);
    }
    __syncthreads();
  }
#pragma unroll
  for (int i = 0; i < 4; ++i)
#pragma unroll
    for (int j = 0; j < 4; ++j)
#pragma unroll
      for (int r = 0; r < 4; ++r) {
        int m = m0 + wr * 64 + i * 16 + l4 * 4 + r;
        int n = n0 + wc * 64 + j * 16 + l15;
        C[(size_t)m * N + n] = acc[i][j][r];
      }
}

// ---------------- fused RMSNorm + RoPE ----------------
__global__ __launch_bounds__(256) void norm_rope(const float* __restrict__ QKV,
                                                 const float* __restrict__ cosT,
                                                 const float* __restrict__ sinT,
                                                 const float* __restrict__ qw,
                                                 const float* __restrict__ kw,
                                                 unsigned short* __restrict__ qo,
                                                 unsigned short* __restrict__ ko) {
  int bs = blockIdx.x;
  int b = bs >> 11, s = bs & 2047;
  int t = threadIdx.x, hu = t >> 3, l8 = t & 7;
  if (hu >= 24) return;
  bool isq = hu < 16;
  int h = isq ? hu : hu - 16;
  const float* x = QKV + (size_t)bs * 4096 + (isq ? h * 128 : 2048 + h * 128);
  int d0 = l8 * 8;
  float x1[8] __attribute__((aligned(16)));
  float x2[8] __attribute__((aligned(16)));
  *(float4*)(x1) = *(const float4*)(x + d0);
  *(float4*)(x1 + 4) = *(const float4*)(x + d0 + 4);
  *(float4*)(x2) = *(const float4*)(x + d0 + 64);
  *(float4*)(x2 + 4) = *(const float4*)(x + d0 + 68);
  float ss = 0.f;
#pragma unroll
  for (int j = 0; j < 8; ++j) ss += x1[j] * x1[j] + x2[j] * x2[j];
  ss += __shfl_xor(ss, 1);
  ss += __shfl_xor(ss, 2);
  ss += __shfl_xor(ss, 4);
  float rstd = rsqrtf(ss * 0.0078125f + 1e-6f);
  const float* wn = isq ? qw : kw;
  float c[8] __attribute__((aligned(16)));
  float sn[8] __attribute__((aligned(16)));
  *(float4*)(c) = *(const float4*)(cosT + s * 64 + d0);
  *(float4*)(c + 4) = *(const float4*)(cosT + s * 64 + d0 + 4);
  *(float4*)(sn) = *(const float4*)(sinT + s * 64 + d0);
  *(float4*)(sn + 4) = *(const float4*)(sinT + s * 64 + d0 + 4);
  bf16x8 o1, o2;
#pragma unroll
  for (int j = 0; j < 8; ++j) {
    float a = x1[j] * rstd * wn[d0 + j];
    float bb = x2[j] * rstd * wn[d0 + 64 + j];
    o1[j] = (short)f2bf(a * c[j] - bb * sn[j]);
    o2[j] = (short)f2bf(bb * c[j] + a * sn[j]);
  }
  unsigned short* dst = isq ? qo + ((size_t)(b * 16 + h) * 2048 + s) * 128
                            : ko + ((size_t)(b * 8 + h) * 2048 + s) * 128;
  *(bf16x8*)(dst + d0) = o1;
  *(bf16x8*)(dst + d0 + 64) = o2;
}

// ---------------- V transpose: qkv f32 -> vT bf16 [b,hkv,d,s]
__global__ __launch_bounds__(256) void transpose_v(const float* __restrict__ QKV,
                                                   unsigned short* __restrict__ vT) {
  __shared__ unsigned short tile[64][68];
  int bid = blockIdx.x;
  int hid = bid >> 6;
  int st = (bid >> 1) & 31, dt = bid & 1;
  int b = hid >> 3, hkv = hid & 7;
  int t = threadIdx.x;
#pragma unroll
  for (int i = 0; i < 16; ++i) {
    int idx = t + i * 256;
    int sl = idx >> 6, dl = idx & 63;
    float v = QKV[(size_t)(b * 2048 + st * 64 + sl) * 4096 + 3072 + hkv * 128 + dt * 64 + dl];
    tile[sl][dl] = f2bf(v);
  }
  __syncthreads();
#pragma unroll
  for (int i = 0; i < 16; ++i) {
    int idx = t + i * 256;
    int dl = idx >> 6, sl = idx & 63;
    vT[((size_t)(b * 8 + hkv) * 128 + dt * 64 + dl) * 2048 + st * 64 + sl] = tile[sl][dl];
  }
}

// ---------------- causal GQA flash attention, PAIR-BALANCED ----------------
// grid (pair=16, h=16, b=2), 256 thr = 4 waves. Block pr handles q-tiles
// {pr, 31-pr} SEQUENTIALLY: (pr+1)+(32-pr) = 33 KV-iterations for EVERY block
// (uniform duration -> no causal tail imbalance; was qt+1 in [1..32]).
__global__ __launch_bounds__(256) void attn_fwd(const unsigned short* __restrict__ Q,
                                                const unsigned short* __restrict__ Kb,
                                                const unsigned short* __restrict__ Vt,
                                                unsigned short* __restrict__ Ao) {
  __shared__ __align__(16) char lds[41984];  // K:16KB, VT:16KB, P: 4x2304B
  const int pr = blockIdx.x, h = blockIdx.y, b = blockIdx.z;
  const int hkv = h >> 1;
  const int t = threadIdx.x, w = t >> 6, lane = t & 63;
  const int l15 = lane & 15, l4 = lane >> 4;

  const unsigned short* Kg = Kb + ((size_t)(b * 8 + hkv) * 2048) * 128;
  const unsigned short* Vg = Vt + ((size_t)(b * 8 + hkv) * 128) * 2048;
  char* Pb = lds + 32768 + w * 2304;

  for (int hh = 0; hh < 2; ++hh) {
    const int qt = hh ? 31 - pr : pr;
    const int qrow0 = qt * 64;

    // Q fragments in regs: row = w*16 + (lane&15), k-chunks of 32
    bf16x8 qf[4];
    const unsigned short* qp =
        Q + ((size_t)(b * 16 + h) * 2048 + qrow0 + w * 16 + l15) * 128;
#pragma unroll
    for (int c = 0; c < 4; ++c) qf[c] = *(const bf16x8*)(qp + c * 32 + l4 * 8);

    float mrow[4], lrow[4];
    f32x4 o[8];
#pragma unroll
    for (int r = 0; r < 4; ++r) { mrow[r] = -1e30f; lrow[r] = 0.f; }
#pragma unroll
    for (int dn = 0; dn < 8; ++dn) o[dn] = (f32x4){0.f, 0.f, 0.f, 0.f};

    for (int tt = 0; tt <= qt; ++tt) {
      __syncthreads();  // prev iter's LDS reads done before restage
      // stage K tile [64][256B rows], swizzled source
#pragma unroll
      for (int j = 0; j < 4; ++j) {
        int ob = ((w * 4 + j) << 10) + (lane << 4);
        int row = ob >> 8, inrow = ob & 255;
        int src = inrow ^ ((row & 7) << 4);
        gload16((const char*)(Kg + (size_t)tt * 64 * 128) + row * 256 + src,
                lds + ((w * 4 + j) << 10));
      }
      // stage VT tile [128][128B rows], swizzled source
#pragma unroll
      for (int j = 0; j < 4; ++j) {
        int ob = ((w * 4 + j) << 10) + (lane << 4);
        int row = ob >> 7, inrow = ob & 127;
        int src = inrow ^ ((row & 7) << 4);
        gload16((const char*)Vg + (size_t)row * 4096 + tt * 128 + src,
                lds + 16384 + ((w * 4 + j) << 10));
      }
      __syncthreads();

      // QK^T: scores [16 q][64 kv] per wave
      f32x4 sacc[4];
#pragma unroll
      for (int n = 0; n < 4; ++n) sacc[n] = (f32x4){0.f, 0.f, 0.f, 0.f};
#pragma unroll
      for (int c = 0; c < 4; ++c) {
#pragma unroll
        for (int n = 0; n < 4; ++n) {
          int rowl = n * 16 + l15;
          int inr = c * 64 + l4 * 16;
          bf16x8 kf = *(const bf16x8*)(lds + rowl * 256 + (inr ^ ((rowl & 7) << 4)));
          sacc[n] = __builtin_amdgcn_mfma_f32_16x16x32_bf16(qf[c], kf, sacc[n], 0, 0, 0);
        }
      }

      // online softmax (lane holds rows l4*4+r, cols n*16+l15)
      float sc[4][4];
      bool diag = (tt == qt);
#pragma unroll
      for (int n = 0; n < 4; ++n)
#pragma unroll
        for (int r = 0; r < 4; ++r) {
          float v = sacc[n][r] * SCALE_;
          if (diag && (tt * 64 + n * 16 + l15 > qrow0 + w * 16 + l4 * 4 + r)) v = -1e30f;
          sc[n][r] = v;
        }
      float al[4];
#pragma unroll
      for (int r = 0; r < 4; ++r) {
        float tm = fmaxf(fmaxf(sc[0][r], sc[1][r]), fmaxf(sc[2][r], sc[3][r]));
        tm = fmaxf(tm, __shfl_xor(tm, 1));
        tm = fmaxf(tm, __shfl_xor(tm, 2));
        tm = fmaxf(tm, __shfl_xor(tm, 4));
        tm = fmaxf(tm, __shfl_xor(tm, 8));
        float mn = fmaxf(mrow[r], tm);
        al[r] = __expf(mrow[r] - mn);
        mrow[r] = mn;
      }
      float rs[4] = {0.f, 0.f, 0.f, 0.f};
#pragma unroll
      for (int n = 0; n < 4; ++n)
#pragma unroll
        for (int r = 0; r < 4; ++r) {
          float p = __expf(sc[n][r] - mrow[r]);
          sc[n][r] = p;
          rs[r] += p;
        }
#pragma unroll
      for (int r = 0; r < 4; ++r) {
        rs[r] += __shfl_xor(rs[r], 1);
        rs[r] += __shfl_xor(rs[r], 2);
        rs[r] += __shfl_xor(rs[r], 4);
        rs[r] += __shfl_xor(rs[r], 8);
        lrow[r] = lrow[r] * al[r] + rs[r];
      }
#pragma unroll
      for (int dn = 0; dn < 8; ++dn)
#pragma unroll
        for (int r = 0; r < 4; ++r) o[dn][r] *= al[r];

      // P -> LDS (per-wave [16][72] padded bf16), re-fragment as A-operand
      unsigned short* Pp = (unsigned short*)Pb;
#pragma unroll
      for (int n = 0; n < 4; ++n)
#pragma unroll
        for (int r = 0; r < 4; ++r)
          Pp[(l4 * 4 + r) * 72 + n * 16 + l15] = f2bf(sc[n][r]);
      __syncthreads();

      // PV: O += P[16][64] * V[64][128]
#pragma unroll
      for (int c2 = 0; c2 < 2; ++c2) {
        bf16x8 pf = *(const bf16x8*)(Pb + l15 * 144 + c2 * 64 + l4 * 16);
#pragma unroll
        for (int dn = 0; dn < 8; ++dn) {
          int rowv = dn * 16 + l15;
          int inr = c2 * 64 + l4 * 16;
          bf16x8 vf = *(const bf16x8*)(lds + 16384 + rowv * 128 + (inr ^ ((rowv & 7) << 4)));
          o[dn] = __builtin_amdgcn_mfma_f32_16x16x32_bf16(pf, vf, o[dn], 0, 0, 0);
        }
      }
    }

    // normalize + write bf16 attn out [B,S,NH*HD]
#pragma unroll
    for (int r = 0; r < 4; ++r) {
      float inv = 1.f / lrow[r];
#pragma unroll
      for (int dn = 0; dn < 8; ++dn) {
        Ao[(size_t)(b * 2048 + qrow0 + w * 16 + l4 * 4 + r) * 2048 + h * 128 +
           dn * 16 + l15] = f2bf(o[dn][r] * inv);
      }
    }
  }
}

// ---------------- launch ----------------
extern "C" void kernel_launch(void* const* d_in, const int* in_sizes, int n_in,
                              void* d_out, int out_size, void* d_ws, size_t ws_size,
                              hipStream_t stream) {
  const float* hidden = (const float*)d_in[0];
  const float* cosT = (const float*)d_in[1];
  const float* sinT = (const float*)d_in[2];
  const float* wqkv = (const float*)d_in[3];
  const float* qw = (const float*)d_in[4];
  const float* kw = (const float*)d_in[5];
  const float* wo = (const float*)d_in[6];
  float* out = (float*)d_out;
  char* ws = (char*)d_ws;

  unsigned short* Xb = (unsigned short*)(ws);                    // 16 MB
  unsigned short* Wqkvb = (unsigned short*)(ws + 16777216);      // 16 MB
  unsigned short* Wob = (unsigned short*)(ws + 33554432);        // 8 MB
  float* QKV = (float*)(ws + 41943040);                          // 64 MB
  unsigned short* Qb = (unsigned short*)(ws + 109051904);        // 16 MB
  unsigned short* Kbuf = (unsigned short*)(ws + 125829120);      // 8 MB
  unsigned short* VT = (unsigned short*)(ws + 134217728);        // 8 MB
  unsigned short* An = (unsigned short*)(ws + 142606336);        // 16 MB

  cvt_bf16<<<8192, 256, 0, stream>>>(hidden, Xb, 2097152);
  cvt_bf16<<<8192, 256, 0, stream>>>(wqkv, Wqkvb, 2097152);
  cvt_bf16<<<4096, 256, 0, stream>>>(wo, Wob, 1048576);

  gemm_bt<<<dim3(32, 32), 256, 0, stream>>>(Xb, Wqkvb, QKV, 4096, 4096, 2048);

  norm_rope<<<4096, 256, 0, stream>>>(QKV, cosT, sinT, qw, kw, Qb, Kbuf);
  transpose_v<<<1024, 256, 0, stream>>>(QKV, VT);

  attn_fwd<<<dim3(16, 16, 2), 256, 0, stream>>>(Qb, Kbuf, VT, An);

  gemm_bt<<<dim3(16, 32), 256, 0, stream>>>(An, Wob, out, 4096, 2048, 2048);
}

// Round 12
// 365.866 us; speedup vs baseline: 1.2129x; 1.0221x over previous
//
#include <hip/hip_runtime.h>
#include <stdint.h>
#include <stddef.h>

// ---------------- types / helpers ----------------
typedef __attribute__((ext_vector_type(8))) short bf16x8;
typedef __attribute__((ext_vector_type(4))) float f32x4;

#define B_ 2
#define S_ 2048
#define HID_ 2048
#define NH_ 16
#define NKV_ 8
#define HD_ 128
#define SCALE_ 0.08838834764831843f

__device__ __forceinline__ unsigned short f2bf(float f) {
  union { float f; unsigned int u; } v; v.f = f;
  unsigned int r = v.u + 0x7fffu + ((v.u >> 16) & 1u);  // RNE
  return (unsigned short)(r >> 16);
}

// async global->LDS, 16B per lane. Dest must be wave-uniform base (HW adds lane*16).
__device__ __forceinline__ void gload16(const void* g, void* l) {
  __builtin_amdgcn_global_load_lds(
      (const __attribute__((address_space(1))) unsigned int*)g,
      (__attribute__((address_space(3))) unsigned int*)l, 16, 0, 0);
}

// ---------------- fp32 -> bf16 convert ----------------
__global__ __launch_bounds__(256) void cvt_bf16(const float* __restrict__ src,
                                                unsigned short* __restrict__ dst,
                                                int n4) {
  int i = blockIdx.x * 256 + threadIdx.x;
  if (i < n4) {
    float4 v = ((const float4*)src)[i];
    ushort4 o;
    o.x = f2bf(v.x); o.y = f2bf(v.y); o.z = f2bf(v.z); o.w = f2bf(v.w);
    ((ushort4*)dst)[i] = o;
  }
}

// ---------------- bf16 GEMM, C = A(MxK) * Bw(NxK)^T, fp32 out ----------------
// 128x128 tile, BK=64, 4 waves (2x2), 16x16x32 MFMA.  (m97-class structure)
__global__ __launch_bounds__(256) void gemm_bt(const unsigned short* __restrict__ A,
                                               const unsigned short* __restrict__ Bw,
                                               float* __restrict__ C,
                                               int M, int N, int K) {
  __shared__ __align__(16) char lds[32768];  // A:0..16383, B:16384..32767
  const int t = threadIdx.x, w = t >> 6, lane = t & 63;
  const int m0 = blockIdx.y * 128, n0 = blockIdx.x * 128;
  const int wr = w >> 1, wc = w & 1;
  const int l15 = lane & 15, l4 = lane >> 4;

  f32x4 acc[4][4];
#pragma unroll
  for (int i = 0; i < 4; ++i)
#pragma unroll
    for (int j = 0; j < 4; ++j) acc[i][j] = (f32x4){0.f, 0.f, 0.f, 0.f};

  const int nk = K >> 6;
  for (int kt = 0; kt < nk; ++kt) {
#pragma unroll
    for (int j = 0; j < 4; ++j) {
      int ob = ((w * 4 + j) << 10) + (lane << 4);
      int row = ob >> 7, inrow = ob & 127;
      int src = inrow ^ ((row & 7) << 4);
      gload16((const char*)A + ((size_t)(m0 + row) * K + kt * 64) * 2 + src,
              lds + ((w * 4 + j) << 10));
    }
#pragma unroll
    for (int j = 0; j < 4; ++j) {
      int ob = ((w * 4 + j) << 10) + (lane << 4);
      int row = ob >> 7, inrow = ob & 127;
      int src = inrow ^ ((row & 7) << 4);
      gload16((const char*)Bw + ((size_t)(n0 + row) * K + kt * 64) * 2 + src,
              lds + 16384 + ((w * 4 + j) << 10));
    }
    __syncthreads();
#pragma unroll
    for (int c = 0; c < 2; ++c) {
      bf16x8 af[4], bfr[4];
#pragma unroll
      for (int i = 0; i < 4; ++i) {
        int rowl = wr * 64 + i * 16 + l15;
        int inr = c * 64 + l4 * 16;
        af[i] = *(const bf16x8*)(lds + rowl * 128 + (inr ^ ((rowl & 7) << 4)));
      }
#pragma unroll
      for (int j = 0; j < 4; ++j) {
        int rowl = wc * 64 + j * 16 + l15;
        int inr = c * 64 + l4 * 16;
        bfr[j] = *(const bf16x8*)(lds + 16384 + rowl * 128 + (inr ^ ((rowl & 7) << 4)));
      }
#pragma unroll
      for (int i = 0; i < 4; ++i)
#pragma unroll
        for (int j = 0; j < 4; ++j)
          acc[i][j] = __builtin_amdgcn_mfma_f32_16x16x32_bf16(af[i], bfr[j], acc[i][j], 0, 0, 0);
    }
    __syncthreads();
  }
#pragma unroll
  for (int i = 0; i < 4; ++i)
#pragma unroll
    for (int j = 0; j < 4; ++j)
#pragma unroll
      for (int r = 0; r < 4; ++r) {
        int m = m0 + wr * 64 + i * 16 + l4 * 4 + r;
        int n = n0 + wc * 64 + j * 16 + l15;
        C[(size_t)m * N + n] = acc[i][j][r];
      }
}

// ---------------- fused RMSNorm + RoPE ----------------
__global__ __launch_bounds__(256) void norm_rope(const float* __restrict__ QKV,
                                                 const float* __restrict__ cosT,
                                                 const float* __restrict__ sinT,
                                                 const float* __restrict__ qw,
                                                 const float* __restrict__ kw,
                                                 unsigned short* __restrict__ qo,
                                                 unsigned short* __restrict__ ko) {
  int bs = blockIdx.x;
  int b = bs >> 11, s = bs & 2047;
  int t = threadIdx.x, hu = t >> 3, l8 = t & 7;
  if (hu >= 24) return;
  bool isq = hu < 16;
  int h = isq ? hu : hu - 16;
  const float* x = QKV + (size_t)bs * 4096 + (isq ? h * 128 : 2048 + h * 128);
  int d0 = l8 * 8;
  float x1[8] __attribute__((aligned(16)));
  float x2[8] __attribute__((aligned(16)));
  *(float4*)(x1) = *(const float4*)(x + d0);
  *(float4*)(x1 + 4) = *(const float4*)(x + d0 + 4);
  *(float4*)(x2) = *(const float4*)(x + d0 + 64);
  *(float4*)(x2 + 4) = *(const float4*)(x + d0 + 68);
  float ss = 0.f;
#pragma unroll
  for (int j = 0; j < 8; ++j) ss += x1[j] * x1[j] + x2[j] * x2[j];
  ss += __shfl_xor(ss, 1);
  ss += __shfl_xor(ss, 2);
  ss += __shfl_xor(ss, 4);
  float rstd = rsqrtf(ss * 0.0078125f + 1e-6f);
  const float* wn = isq ? qw : kw;
  float c[8] __attribute__((aligned(16)));
  float sn[8] __attribute__((aligned(16)));
  *(float4*)(c) = *(const float4*)(cosT + s * 64 + d0);
  *(float4*)(c + 4) = *(const float4*)(cosT + s * 64 + d0 + 4);
  *(float4*)(sn) = *(const float4*)(sinT + s * 64 + d0);
  *(float4*)(sn + 4) = *(const float4*)(sinT + s * 64 + d0 + 4);
  bf16x8 o1, o2;
#pragma unroll
  for (int j = 0; j < 8; ++j) {
    float a = x1[j] * rstd * wn[d0 + j];
    float bb = x2[j] * rstd * wn[d0 + 64 + j];
    o1[j] = (short)f2bf(a * c[j] - bb * sn[j]);
    o2[j] = (short)f2bf(bb * c[j] + a * sn[j]);
  }
  unsigned short* dst = isq ? qo + ((size_t)(b * 16 + h) * 2048 + s) * 128
                            : ko + ((size_t)(b * 8 + h) * 2048 + s) * 128;
  *(bf16x8*)(dst + d0) = o1;
  *(bf16x8*)(dst + d0 + 64) = o2;
}

// ---------------- V transpose: qkv f32 -> vT bf16 [b,hkv,d,s]
__global__ __launch_bounds__(256) void transpose_v(const float* __restrict__ QKV,
                                                   unsigned short* __restrict__ vT) {
  __shared__ unsigned short tile[64][68];
  int bid = blockIdx.x;
  int hid = bid >> 6;
  int st = (bid >> 1) & 31, dt = bid & 1;
  int b = hid >> 3, hkv = hid & 7;
  int t = threadIdx.x;
#pragma unroll
  for (int i = 0; i < 16; ++i) {
    int idx = t + i * 256;
    int sl = idx >> 6, dl = idx & 63;
    float v = QKV[(size_t)(b * 2048 + st * 64 + sl) * 4096 + 3072 + hkv * 128 + dt * 64 + dl];
    tile[sl][dl] = f2bf(v);
  }
  __syncthreads();
#pragma unroll
  for (int i = 0; i < 16; ++i) {
    int idx = t + i * 256;
    int dl = idx >> 6, sl = idx & 63;
    vT[((size_t)(b * 8 + hkv) * 128 + dt * 64 + dl) * 2048 + st * 64 + sl] = tile[sl][dl];
  }
}

// ---------------- causal GQA flash attention ----------------
// PAIR-BALANCED + DOUBLE-BUFFERED (T3-min 2-phase):
// grid (pair=16, h=16, b=2), 256 thr = 4 waves. Block pr does q-tiles
// {pr, 31-pr} sequentially (33 KV-iters uniform). Per iteration:
//   STAGE(next tile -> other buf) ; compute current ; ONE __syncthreads().
// __syncthreads() drains vmcnt+lgkmcnt (compiler-emitted) so the staged
// buffer is visible; buffer overwritten at t+1 was last read at t (safe).
// P buffers are per-wave: write->read is same-wave lgkmcnt, no barrier.
__global__ __launch_bounds__(256) void attn_fwd(const unsigned short* __restrict__ Q,
                                                const unsigned short* __restrict__ Kb,
                                                const unsigned short* __restrict__ Vt,
                                                unsigned short* __restrict__ Ao) {
  // buf i: K at i*32768 (64 rows x 256B), V at i*32768+16384 (128 rows x 128B)
  // P: 65536 + w*2304  ([16][72] bf16, padded)
  __shared__ __align__(16) char lds[74752];
  const int pr = blockIdx.x, h = blockIdx.y, b = blockIdx.z;
  const int hkv = h >> 1;
  const int t = threadIdx.x, w = t >> 6, lane = t & 63;
  const int l15 = lane & 15, l4 = lane >> 4;

  const unsigned short* Kg = Kb + ((size_t)(b * 8 + hkv) * 2048) * 128;
  const unsigned short* Vg = Vt + ((size_t)(b * 8 + hkv) * 128) * 2048;
  char* Pb = lds + 65536 + w * 2304;

  // stage K/V tile tt2 into buffer bufi (8 x gload16 per wave)
  auto STAGE = [&](int bufi, int tt2) {
    char* kb = lds + bufi * 32768;
    char* vb = kb + 16384;
#pragma unroll
    for (int j = 0; j < 4; ++j) {
      int ob = ((w * 4 + j) << 10) + (lane << 4);
      int row = ob >> 8, inrow = ob & 255;
      int src = inrow ^ ((row & 7) << 4);
      gload16((const char*)(Kg + (size_t)tt2 * 64 * 128) + row * 256 + src,
              kb + ((w * 4 + j) << 10));
    }
#pragma unroll
    for (int j = 0; j < 4; ++j) {
      int ob = ((w * 4 + j) << 10) + (lane << 4);
      int row = ob >> 7, inrow = ob & 127;
      int src = inrow ^ ((row & 7) << 4);
      gload16((const char*)Vg + (size_t)row * 4096 + tt2 * 128 + src,
              vb + ((w * 4 + j) << 10));
    }
  };

  for (int hh = 0; hh < 2; ++hh) {
    const int qt = hh ? 31 - pr : pr;
    const int qrow0 = qt * 64;

    // Q fragments in regs: row = w*16 + (lane&15), k-chunks of 32
    bf16x8 qf[4];
    const unsigned short* qp =
        Q + ((size_t)(b * 16 + h) * 2048 + qrow0 + w * 16 + l15) * 128;
#pragma unroll
    for (int c = 0; c < 4; ++c) qf[c] = *(const bf16x8*)(qp + c * 32 + l4 * 8);

    float mrow[4], lrow[4];
    f32x4 o[8];
#pragma unroll
    for (int r = 0; r < 4; ++r) { mrow[r] = -1e30f; lrow[r] = 0.f; }
#pragma unroll
    for (int dn = 0; dn < 8; ++dn) o[dn] = (f32x4){0.f, 0.f, 0.f, 0.f};

    int cur = 0;
    STAGE(0, 0);
    __syncthreads();  // prologue drain (also retires prev hh's last reads)

    for (int tt = 0; tt <= qt; ++tt) {
      if (tt < qt) STAGE(cur ^ 1, tt + 1);  // prefetch next tile (latency hides)
      const char* kb = lds + cur * 32768;
      const char* vb = kb + 16384;

      // QK^T: scores [16 q][64 kv] per wave
      f32x4 sacc[4];
#pragma unroll
      for (int n = 0; n < 4; ++n) sacc[n] = (f32x4){0.f, 0.f, 0.f, 0.f};
#pragma unroll
      for (int c = 0; c < 4; ++c) {
#pragma unroll
        for (int n = 0; n < 4; ++n) {
          int rowl = n * 16 + l15;
          int inr = c * 64 + l4 * 16;
          bf16x8 kf = *(const bf16x8*)(kb + rowl * 256 + (inr ^ ((rowl & 7) << 4)));
          sacc[n] = __builtin_amdgcn_mfma_f32_16x16x32_bf16(qf[c], kf, sacc[n], 0, 0, 0);
        }
      }

      // online softmax (lane holds rows l4*4+r, cols n*16+l15)
      float sc[4][4];
      bool diag = (tt == qt);
#pragma unroll
      for (int n = 0; n < 4; ++n)
#pragma unroll
        for (int r = 0; r < 4; ++r) {
          float v = sacc[n][r] * SCALE_;
          if (diag && (tt * 64 + n * 16 + l15 > qrow0 + w * 16 + l4 * 4 + r)) v = -1e30f;
          sc[n][r] = v;
        }
      float al[4];
#pragma unroll
      for (int r = 0; r < 4; ++r) {
        float tm = fmaxf(fmaxf(sc[0][r], sc[1][r]), fmaxf(sc[2][r], sc[3][r]));
        tm = fmaxf(tm, __shfl_xor(tm, 1));
        tm = fmaxf(tm, __shfl_xor(tm, 2));
        tm = fmaxf(tm, __shfl_xor(tm, 4));
        tm = fmaxf(tm, __shfl_xor(tm, 8));
        float mn = fmaxf(mrow[r], tm);
        al[r] = __expf(mrow[r] - mn);
        mrow[r] = mn;
      }
      float rs[4] = {0.f, 0.f, 0.f, 0.f};
#pragma unroll
      for (int n = 0; n < 4; ++n)
#pragma unroll
        for (int r = 0; r < 4; ++r) {
          float p = __expf(sc[n][r] - mrow[r]);
          sc[n][r] = p;
          rs[r] += p;
        }
#pragma unroll
      for (int r = 0; r < 4; ++r) {
        rs[r] += __shfl_xor(rs[r], 1);
        rs[r] += __shfl_xor(rs[r], 2);
        rs[r] += __shfl_xor(rs[r], 4);
        rs[r] += __shfl_xor(rs[r], 8);
        lrow[r] = lrow[r] * al[r] + rs[r];
      }
#pragma unroll
      for (int dn = 0; dn < 8; ++dn)
#pragma unroll
        for (int r = 0; r < 4; ++r) o[dn][r] *= al[r];

      // P -> per-wave LDS [16][72] bf16; same-wave write->read (lgkmcnt only)
      unsigned short* Pp = (unsigned short*)Pb;
#pragma unroll
      for (int n = 0; n < 4; ++n)
#pragma unroll
        for (int r = 0; r < 4; ++r)
          Pp[(l4 * 4 + r) * 72 + n * 16 + l15] = f2bf(sc[n][r]);

      // PV: O += P[16][64] * V[64][128]
#pragma unroll
      for (int c2 = 0; c2 < 2; ++c2) {
        bf16x8 pf = *(const bf16x8*)(Pb + l15 * 144 + c2 * 64 + l4 * 16);
#pragma unroll
        for (int dn = 0; dn < 8; ++dn) {
          int rowv = dn * 16 + l15;
          int inr = c2 * 64 + l4 * 16;
          bf16x8 vf = *(const bf16x8*)(vb + rowv * 128 + (inr ^ ((rowv & 7) << 4)));
          o[dn] = __builtin_amdgcn_mfma_f32_16x16x32_bf16(pf, vf, o[dn], 0, 0, 0);
        }
      }

      __syncthreads();  // single barrier: drains stage loads, retires buf reads
      cur ^= 1;
    }

    // normalize + write bf16 attn out [B,S,NH*HD]
#pragma unroll
    for (int r = 0; r < 4; ++r) {
      float inv = 1.f / lrow[r];
#pragma unroll
      for (int dn = 0; dn < 8; ++dn) {
        Ao[(size_t)(b * 2048 + qrow0 + w * 16 + l4 * 4 + r) * 2048 + h * 128 +
           dn * 16 + l15] = f2bf(o[dn][r] * inv);
      }
    }
  }
}

// ---------------- launch ----------------
extern "C" void kernel_launch(void* const* d_in, const int* in_sizes, int n_in,
                              void* d_out, int out_size, void* d_ws, size_t ws_size,
                              hipStream_t stream) {
  const float* hidden = (const float*)d_in[0];
  const float* cosT = (const float*)d_in[1];
  const float* sinT = (const float*)d_in[2];
  const float* wqkv = (const float*)d_in[3];
  const float* qw = (const float*)d_in[4];
  const float* kw = (const float*)d_in[5];
  const float* wo = (const float*)d_in[6];
  float* out = (float*)d_out;
  char* ws = (char*)d_ws;

  unsigned short* Xb = (unsigned short*)(ws);                    // 16 MB
  unsigned short* Wqkvb = (unsigned short*)(ws + 16777216);      // 16 MB
  unsigned short* Wob = (unsigned short*)(ws + 33554432);        // 8 MB
  float* QKV = (float*)(ws + 41943040);                          // 64 MB
  unsigned short* Qb = (unsigned short*)(ws + 109051904);        // 16 MB
  unsigned short* Kbuf = (unsigned short*)(ws + 125829120);      // 8 MB
  unsigned short* VT = (unsigned short*)(ws + 134217728);        // 8 MB
  unsigned short* An = (unsigned short*)(ws + 142606336);        // 16 MB

  cvt_bf16<<<8192, 256, 0, stream>>>(hidden, Xb, 2097152);
  cvt_bf16<<<8192, 256, 0, stream>>>(wqkv, Wqkvb, 2097152);
  cvt_bf16<<<4096, 256, 0, stream>>>(wo, Wob, 1048576);

  gemm_bt<<<dim3(32, 32), 256, 0, stream>>>(Xb, Wqkvb, QKV, 4096, 4096, 2048);

  norm_rope<<<4096, 256, 0, stream>>>(QKV, cosT, sinT, qw, kw, Qb, Kbuf);
  transpose_v<<<1024, 256, 0, stream>>>(QKV, VT);

  attn_fwd<<<dim3(16, 16, 2), 256, 0, stream>>>(Qb, Kbuf, VT, An);

  gemm_bt<<<dim3(16, 32), 256, 0, stream>>>(An, Wob, out, 4096, 2048, 2048);
}